// Round 2
// 1101.095 us; speedup vs baseline: 1.0079x; 1.0079x over previous
//
#include <hip/hip_runtime.h>

// B=8, C=128, T=128, F=512, K=64 — bf16 MFMA pipeline (32x32x16 + 16x16x32)
static constexpr int Cc = 128, Tt = 128, Ff = 512, Kk = 64;
static constexpr int SR = 136;  // LDS activation row stride (bf16 elems), [64 f][136 c]
static constexpr int PR = 88;   // LDS P-matrix row stride

typedef __bf16 bf16x8 __attribute__((ext_vector_type(8)));
typedef __bf16 bf16x4 __attribute__((ext_vector_type(4)));
typedef float f32x16 __attribute__((ext_vector_type(16)));
typedef float f32x4 __attribute__((ext_vector_type(4)));

__device__ __forceinline__ f32x16 z16() {
  f32x16 v;
#pragma unroll
  for (int i = 0; i < 16; ++i) v[i] = 0.f;
  return v;
}
__device__ __forceinline__ f32x4 z4() {
  f32x4 v;
#pragma unroll
  for (int i = 0; i < 4; ++i) v[i] = 0.f;
  return v;
}
__device__ __forceinline__ float silu_f(float x) { return x / (1.0f + __expf(-x)); }

// RMSNorm over c (=128) per f-row of an LDS [64][SR] bf16 tile. dst may == src.
// Barrier-free: thread (f=tid>>2, s2=tid&3) owns c in [s2*32, s2*32+32); the
// 4-thread group shares one f-row -> 2-step shfl_xor reduce. Values stay in
// registers between the sum pass and the normalize pass (no LDS re-read).
// Caller must __syncthreads() before (src complete) and after (dst consumed).
__device__ __forceinline__ void rmsnorm_lds(const __bf16* __restrict__ src,
                                            __bf16* __restrict__ dst,
                                            const float* __restrict__ gamma, int tid) {
  const int f = tid >> 2, s2 = tid & 3;
  const __bf16* p = src + f * SR + s2 * 32;
  bf16x8 v[4];
  float sum = 0.f;
#pragma unroll
  for (int k = 0; k < 4; ++k) {
    v[k] = *(const bf16x8*)(p + k * 8);
#pragma unroll
    for (int j = 0; j < 8; ++j) { float x = (float)v[k][j]; sum += x * x; }
  }
  sum += __shfl_xor(sum, 1);
  sum += __shfl_xor(sum, 2);
  const float r = rsqrtf(sum * (1.f / 128.f) + 1e-6f);
  __bf16* q = dst + f * SR + s2 * 32;
#pragma unroll
  for (int k = 0; k < 4; ++k) {
    bf16x8 w;
#pragma unroll
    for (int j = 0; j < 8; ++j)
      w[j] = (__bf16)((float)v[k][j] * r * gamma[s2 * 32 + k * 8 + j]);
    *(bf16x8*)(q + k * 8) = w;
  }
}

// Y^T[f][o] = sum_c X[f][c] * W[o][c]; X = LDS [64][SR] bf16 (A-op), W = global bf16
// row-major [>=128][128] (B-op). 4 waves: wave = (o-pair <<1) | f-tile. Each wave: two
// 32x32 D tiles (t=0,1 -> o base p*64 + t*32). epi(acc, t) handles bias/act/store.
template <typename EPI>
__device__ __forceinline__ void unit_std(const __bf16* __restrict__ X,
                                         const __bf16* __restrict__ W,
                                         int lane, int wave, EPI epi) {
  const int h = lane >> 5, ol = lane & 31;
  const int p = wave >> 1, mt = wave & 1;
  const int oA = p * 64 + ol;
  bf16x8 B0[8], B1[8];
#pragma unroll
  for (int s = 0; s < 8; ++s) {
    B0[s] = *(const bf16x8*)(W + (size_t)oA * 128 + s * 16 + h * 8);
    B1[s] = *(const bf16x8*)(W + (size_t)(oA + 32) * 128 + s * 16 + h * 8);
  }
  f32x16 a0 = z16(), a1 = z16();
  const __bf16* Ar = X + (mt * 32 + ol) * SR + h * 8;
#pragma unroll
  for (int s = 0; s < 8; ++s) {
    bf16x8 Af = *(const bf16x8*)(Ar + s * 16);
    a0 = __builtin_amdgcn_mfma_f32_32x32x16_bf16(Af, B0[s], a0, 0, 0, 0);
    a1 = __builtin_amdgcn_mfma_f32_32x32x16_bf16(Af, B1[s], a1, 0, 0, 0);
  }
  epi(a0, 0);
  epi(a1, 1);
}

// ---------------- weight conversion ----------------
struct PrepArgs {
  const float* src[9];
  int n[9];
};
__global__ __launch_bounds__(256) void prep_kernel(PrepArgs pa, __bf16* __restrict__ dst) {
  int off = 0;
  for (int m = 0; m < 9; ++m) {
    const float* s = pa.src[m];
    int n = pa.n[m];
    for (int i = blockIdx.x * 256 + threadIdx.x; i < n; i += gridDim.x * 256)
      dst[off + i] = (__bf16)s[i];
    off += n;
  }
}

// ---------------- kv kernel ----------------
// LDS = 2*17408 = 34816 B -> 4 blocks/CU.
__global__ __launch_bounds__(256, 4)
void kv_kernel(const float* __restrict__ latent, const float* __restrict__ lp_gamma,
               const float* __restrict__ lp_b, const float* __restrict__ k_b,
               const float* __restrict__ v_b,
               const __bf16* __restrict__ w_lp, const __bf16* __restrict__ w_k,
               const __bf16* __restrict__ w_v,
               __bf16* __restrict__ kbuf, __bf16* __restrict__ vbuf) {
  __shared__ __align__(16) __bf16 S0[64 * SR];
  __shared__ __align__(16) __bf16 S1[64 * SR];
  const int tid = threadIdx.x;
  const int lane = tid & 63, wave = tid >> 6;
  const int h = lane >> 5, ol = lane & 31;
  const int fr = blockIdx.x;
  const int b = fr >> 7, t = fr & 127;
  const size_t lbase = ((size_t)b * Cc * Tt + t) * Kk;

  // load latent [c][kk] -> S0 [kk][c] bf16
#pragma unroll
  for (int i = 0; i < 32; ++i) {
    int idx = i * 256 + tid;
    int c = idx >> 6, kk = idx & 63;
    S0[kk * SR + c] = (__bf16)latent[lbase + (size_t)c * Tt * Kk + kk];
  }
  __syncthreads();
  rmsnorm_lds(S0, S0, lp_gamma, tid);
  __syncthreads();

  // latent_h = silu(lp @ xn + b) -> S1
  unit_std(S0, w_lp, lane, wave, [&](const f32x16& a, int tix) {
    int o = (wave >> 1) * 64 + tix * 32 + ol;
    int mt = wave & 1;
    float bb = lp_b[o];
#pragma unroll
    for (int r = 0; r < 16; ++r) {
      int f = mt * 32 + (r & 3) + 8 * (r >> 2) + 4 * h;
      S1[f * SR + o] = (__bf16)silu_f(a[r] + bb);
    }
  });
  __syncthreads();

  // k -> kbuf [kk][c] (transposed), v -> vbuf [c][kk]
  __bf16* kb = kbuf + (size_t)fr * 8192;
  unit_std(S1, w_k, lane, wave, [&](const f32x16& a, int tix) {
    int o = (wave >> 1) * 64 + tix * 32 + ol;
    int mt = wave & 1;
    float bb = k_b[o];
#pragma unroll
    for (int r = 0; r < 16; ++r) {
      int kkr = mt * 32 + (r & 3) + 8 * (r >> 2) + 4 * h;
      kb[kkr * 128 + o] = (__bf16)(a[r] + bb);
    }
  });
  __bf16* vb = vbuf + (size_t)fr * 8192;
  unit_std(S1, w_v, lane, wave, [&](const f32x16& a, int tix) {
    int o = (wave >> 1) * 64 + tix * 32 + ol;
    int mt = wave & 1;
    float bb = v_b[o];
    __bf16* vbo = vb + (size_t)o * 64 + mt * 32;
#pragma unroll
    for (int q = 0; q < 4; ++q) {
      bf16x4 pk;
      pk[0] = (__bf16)(a[4 * q + 0] + bb);
      pk[1] = (__bf16)(a[4 * q + 1] + bb);
      pk[2] = (__bf16)(a[4 * q + 2] + bb);
      pk[3] = (__bf16)(a[4 * q + 3] + bb);
      *(bf16x4*)(vbo + 8 * q + 4 * h) = pk;
    }
  });
}

// ---------------- main kernel ----------------
// Buffer liveness re-wire so PM can alias S1 (S1 is dead during phases 5-6):
//   ph1: side->S0, rmsnorm S0 in place
//   ph2: qmlp swiglu product -> S1
//   ph3: query_h -> S2
//   ph4: q -> S0
//   ph5: scores+softmax -> PM (=S1 alias; swiglu product dead)
//   ph6: attended^T -> S0 (q dead)
//   ph7: hidden = o@att + skip*S2 -> S1 (PM dead)
//   ph8: rmsnorm(S1) -> S2 (query_h dead)
//   ph9: ffn swiglu product -> S0 (attended dead)
//   ph10: out = fout@S0 + S1(hidden) -> global
// LDS = 3*17408 = 52224 B -> 3 blocks/CU (was 65024 -> 2/CU).
__global__ __launch_bounds__(256, 3)
void main_kernel(const float* __restrict__ side, const float* __restrict__ basis,
                 const float* __restrict__ qn_gamma,
                 const float* __restrict__ qin_b, const float* __restrict__ qout_b,
                 const float* __restrict__ q_b, const float* __restrict__ o_b,
                 const float* __restrict__ ffn_gamma,
                 const float* __restrict__ fin_b, const float* __restrict__ fout_b,
                 const __bf16* __restrict__ w_qin, const __bf16* __restrict__ w_qout,
                 const __bf16* __restrict__ w_q, const __bf16* __restrict__ w_o,
                 const __bf16* __restrict__ w_fin, const __bf16* __restrict__ w_fout,
                 const __bf16* __restrict__ kbuf, const __bf16* __restrict__ vbuf,
                 const float* __restrict__ p_sscale, const float* __restrict__ p_pscale,
                 const float* __restrict__ p_skip, float* __restrict__ out) {
  __shared__ __align__(16) __bf16 S0[64 * SR];
  __shared__ __align__(16) __bf16 S1[64 * SR];
  __shared__ __align__(16) __bf16 S2[64 * SR];
  __bf16* const PM = S1;  // [64][PR] alias, 11264 B <= 17408 B
  const int tid = threadIdx.x;
  const int lane = tid & 63, wave = tid >> 6;
  const int h = lane >> 5, ol = lane & 31;
  const int bid = blockIdx.x;
  const int fr = bid >> 3, tile = bid & 7;
  const int b = fr >> 7, t = fr & 127;
  const int fbase = tile * 64;
  const size_t sbase = ((size_t)b * Cc * Tt + t) * Ff + fbase;
  const float sscale = *p_sscale, pscale = *p_pscale, skip = *p_skip;
  const __bf16* kfr = kbuf + (size_t)fr * 8192;
  const __bf16* vfr = vbuf + (size_t)fr * 8192;

  // phase 1: load side tile -> S0 [f][c] bf16; rmsnorm in place
#pragma unroll
  for (int i = 0; i < 32; ++i) {
    int idx = i * 256 + tid;
    int c = idx >> 6, f = idx & 63;
    S0[f * SR + c] = (__bf16)side[sbase + (size_t)c * Tt * Ff + f];
  }
  __syncthreads();
  rmsnorm_lds(S0, S0, qn_gamma, tid);
  __syncthreads();

  // phase 2: qmlp swiglu: gate then up*silu(gate) -> S1
  {
    float sg[2][16];
    unit_std(S0, w_qin + 128 * 128, lane, wave, [&](const f32x16& a, int tix) {
      int o = (wave >> 1) * 64 + tix * 32 + ol;
      float bb = qin_b[128 + o];
#pragma unroll
      for (int r = 0; r < 16; ++r) sg[tix][r] = silu_f(a[r] + bb);
    });
    unit_std(S0, w_qin, lane, wave, [&](const f32x16& a, int tix) {
      int o = (wave >> 1) * 64 + tix * 32 + ol;
      int mt = wave & 1;
      float bb = qin_b[o];
#pragma unroll
      for (int r = 0; r < 16; ++r) {
        int f = mt * 32 + (r & 3) + 8 * (r >> 2) + 4 * h;
        S1[f * SR + o] = (__bf16)((a[r] + bb) * sg[tix][r]);
      }
    });
  }
  __syncthreads();

  // phase 3: query_h -> S2
  unit_std(S1, w_qout, lane, wave, [&](const f32x16& a, int tix) {
    int o = (wave >> 1) * 64 + tix * 32 + ol;
    int mt = wave & 1;
    float bb = qout_b[o];
#pragma unroll
    for (int r = 0; r < 16; ++r) {
      int f = mt * 32 + (r & 3) + 8 * (r >> 2) + 4 * h;
      S2[f * SR + o] = (__bf16)(a[r] + bb);
    }
  });
  __syncthreads();

  // phase 4: q -> S0
  unit_std(S2, w_q, lane, wave, [&](const f32x16& a, int tix) {
    int o = (wave >> 1) * 64 + tix * 32 + ol;
    int mt = wave & 1;
    float bb = q_b[o];
#pragma unroll
    for (int r = 0; r < 16; ++r) {
      int f = mt * 32 + (r & 3) + 8 * (r >> 2) + 4 * h;
      S0[f * SR + o] = (__bf16)(a[r] + bb);
    }
  });
  __syncthreads();

  // phase 5: scores (16x16x32; wave = f-group of 16) + in-wave softmax -> PM
  {
    const int q4 = lane >> 4, li = lane & 15;
    const int fw = wave * 16;
    f32x4 acc[4] = {z4(), z4(), z4(), z4()};
    const __bf16* Ar = S0 + (fw + li) * SR + q4 * 8;
    const __bf16* Kr = kfr + li * 128 + q4 * 8;
#pragma unroll
    for (int s = 0; s < 4; ++s) {
      bf16x8 Af = *(const bf16x8*)(Ar + s * 32);
#pragma unroll
      for (int nt = 0; nt < 4; ++nt) {
        bf16x8 Bf = *(const bf16x8*)(Kr + nt * (16 * 128) + s * 32);
        acc[nt] = __builtin_amdgcn_mfma_f32_16x16x32_bf16(Af, Bf, acc[nt], 0, 0, 0);
      }
    }
    float sc[4][4];
#pragma unroll
    for (int nt = 0; nt < 4; ++nt)
#pragma unroll
      for (int r = 0; r < 4; ++r) {
        int kk = 16 * nt + li;
        int f = fw + 4 * q4 + r;
        sc[nt][r] = acc[nt][r] * sscale + pscale * basis[(size_t)kk * Ff + fbase + f];
      }
#pragma unroll
    for (int r = 0; r < 4; ++r) {
      float m = fmaxf(fmaxf(sc[0][r], sc[1][r]), fmaxf(sc[2][r], sc[3][r]));
      m = fmaxf(m, __shfl_xor(m, 1));
      m = fmaxf(m, __shfl_xor(m, 2));
      m = fmaxf(m, __shfl_xor(m, 4));
      m = fmaxf(m, __shfl_xor(m, 8));
      float e[4], ssum = 0.f;
#pragma unroll
      for (int nt = 0; nt < 4; ++nt) { e[nt] = __expf(sc[nt][r] - m); ssum += e[nt]; }
      ssum += __shfl_xor(ssum, 1);
      ssum += __shfl_xor(ssum, 2);
      ssum += __shfl_xor(ssum, 4);
      ssum += __shfl_xor(ssum, 8);
      float inv = 1.f / ssum;
      int f = fw + 4 * q4 + r;
#pragma unroll
      for (int nt = 0; nt < 4; ++nt) PM[f * PR + 16 * nt + li] = (__bf16)(e[nt] * inv);
    }
  }
  __syncthreads();

  // phase 6: attended^T[f][c] (wave = c-group of 32) -> S0
  {
    const __bf16* Vr = vfr + (size_t)(wave * 32 + ol) * 64 + h * 8;
    bf16x8 Bv[4];
#pragma unroll
    for (int s = 0; s < 4; ++s) Bv[s] = *(const bf16x8*)(Vr + s * 16);
    f32x16 a0 = z16(), a1 = z16();
    const __bf16* Ar = PM + ol * PR + h * 8;
#pragma unroll
    for (int s = 0; s < 4; ++s) {
      bf16x8 A0 = *(const bf16x8*)(Ar + s * 16);
      bf16x8 A1 = *(const bf16x8*)(Ar + 32 * PR + s * 16);
      a0 = __builtin_amdgcn_mfma_f32_32x32x16_bf16(A0, Bv[s], a0, 0, 0, 0);
      a1 = __builtin_amdgcn_mfma_f32_32x32x16_bf16(A1, Bv[s], a1, 0, 0, 0);
    }
    int c = wave * 32 + ol;
#pragma unroll
    for (int r = 0; r < 16; ++r) {
      int fl = (r & 3) + 8 * (r >> 2) + 4 * h;
      S0[fl * SR + c] = (__bf16)a0[r];
      S0[(32 + fl) * SR + c] = (__bf16)a1[r];
    }
  }
  __syncthreads();

  // phase 7: hidden = o@attended + b + skip*qh -> S1 (PM dead)
  unit_std(S0, w_o, lane, wave, [&](const f32x16& a, int tix) {
    int o = (wave >> 1) * 64 + tix * 32 + ol;
    int mt = wave & 1;
    float bb = o_b[o];
#pragma unroll
    for (int r = 0; r < 16; ++r) {
      int f = mt * 32 + (r & 3) + 8 * (r >> 2) + 4 * h;
      S1[f * SR + o] = (__bf16)(a[r] + bb + skip * (float)S2[f * SR + o]);
    }
  });
  __syncthreads();

  // phase 8: ffn rmsnorm(hidden) -> S2
  rmsnorm_lds(S1, S2, ffn_gamma, tid);
  __syncthreads();

  // phase 9: ffn swiglu -> S0
  {
    float sg[2][16];
    unit_std(S2, w_fin + 128 * 128, lane, wave, [&](const f32x16& a, int tix) {
      int o = (wave >> 1) * 64 + tix * 32 + ol;
      float bb = fin_b[128 + o];
#pragma unroll
      for (int r = 0; r < 16; ++r) sg[tix][r] = silu_f(a[r] + bb);
    });
    unit_std(S2, w_fin, lane, wave, [&](const f32x16& a, int tix) {
      int o = (wave >> 1) * 64 + tix * 32 + ol;
      int mt = wave & 1;
      float bb = fin_b[o];
#pragma unroll
      for (int r = 0; r < 16; ++r) {
        int f = mt * 32 + (r & 3) + 8 * (r >> 2) + 4 * h;
        S0[f * SR + o] = (__bf16)((a[r] + bb) * sg[tix][r]);
      }
    });
  }
  __syncthreads();

  // phase 10: out = fout@prod + b + hidden(S1) -> global (float4 runs of 4 consecutive f)
  unit_std(S0, w_fout, lane, wave, [&](const f32x16& a, int tix) {
    int o = (wave >> 1) * 64 + tix * 32 + ol;
    int mt = wave & 1;
    float bb = fout_b[o];
    float* op = out + (((size_t)b * 128 + o) * 128 + t) * 512 + fbase + mt * 32;
#pragma unroll
    for (int q = 0; q < 4; ++q) {
      int f0l = 8 * q + 4 * h;
      float4 v;
      v.x = a[4 * q + 0] + bb + (float)S1[(mt * 32 + f0l + 0) * SR + o];
      v.y = a[4 * q + 1] + bb + (float)S1[(mt * 32 + f0l + 1) * SR + o];
      v.z = a[4 * q + 2] + bb + (float)S1[(mt * 32 + f0l + 2) * SR + o];
      v.w = a[4 * q + 3] + bb + (float)S1[(mt * 32 + f0l + 3) * SR + o];
      *(float4*)(op + f0l) = v;
    }
  });
}

extern "C" void kernel_launch(void* const* d_in, const int* in_sizes, int n_in,
                              void* d_out, int out_size, void* d_ws, size_t ws_size,
                              hipStream_t stream) {
  const float* latent    = (const float*)d_in[0];
  const float* side      = (const float*)d_in[1];
  const float* basis     = (const float*)d_in[2];
  const float* lp_gamma  = (const float*)d_in[3];
  const float* lp_w      = (const float*)d_in[4];
  const float* lp_b      = (const float*)d_in[5];
  const float* qn_gamma  = (const float*)d_in[6];
  const float* qin_w     = (const float*)d_in[7];
  const float* qin_b     = (const float*)d_in[8];
  const float* qout_w    = (const float*)d_in[9];
  const float* qout_b    = (const float*)d_in[10];
  const float* q_w       = (const float*)d_in[11];
  const float* q_b       = (const float*)d_in[12];
  const float* k_w       = (const float*)d_in[13];
  const float* k_b       = (const float*)d_in[14];
  const float* v_w       = (const float*)d_in[15];
  const float* v_b       = (const float*)d_in[16];
  const float* o_w       = (const float*)d_in[17];
  const float* o_b       = (const float*)d_in[18];
  const float* ffn_gamma = (const float*)d_in[19];
  const float* fin_w     = (const float*)d_in[20];
  const float* fin_b     = (const float*)d_in[21];
  const float* fout_w    = (const float*)d_in[22];
  const float* fout_b    = (const float*)d_in[23];
  const float* sscale    = (const float*)d_in[24];
  const float* pscale    = (const float*)d_in[25];
  const float* skipsc    = (const float*)d_in[26];

  __bf16* wsb = (__bf16*)d_ws;
  __bf16* kbuf = wsb;                                  // 1024*64*128
  __bf16* vbuf = wsb + (size_t)1024 * 8192;            // 1024*128*64
  __bf16* wbase = wsb + (size_t)2048 * 8192;
  // order: lp, qin, qout, q, k, v, o, fin, fout
  __bf16* w_lp   = wbase;
  __bf16* w_qin  = w_lp + 16384;
  __bf16* w_qout = w_qin + 32768;
  __bf16* w_q    = w_qout + 16384;
  __bf16* w_k    = w_q + 16384;
  __bf16* w_v    = w_k + 16384;
  __bf16* w_o    = w_v + 16384;
  __bf16* w_fin  = w_o + 16384;
  __bf16* w_fout = w_fin + 32768;

  PrepArgs pa;
  pa.src[0] = lp_w;   pa.n[0] = 16384;
  pa.src[1] = qin_w;  pa.n[1] = 32768;
  pa.src[2] = qout_w; pa.n[2] = 16384;
  pa.src[3] = q_w;    pa.n[3] = 16384;
  pa.src[4] = k_w;    pa.n[4] = 16384;
  pa.src[5] = v_w;    pa.n[5] = 16384;
  pa.src[6] = o_w;    pa.n[6] = 16384;
  pa.src[7] = fin_w;  pa.n[7] = 32768;
  pa.src[8] = fout_w; pa.n[8] = 16384;

  prep_kernel<<<dim3(64), dim3(256), 0, stream>>>(pa, wbase);
  kv_kernel<<<dim3(1024), dim3(256), 0, stream>>>(
      latent, lp_gamma, lp_b, k_b, v_b, w_lp, w_k, w_v, kbuf, vbuf);
  main_kernel<<<dim3(8192), dim3(256), 0, stream>>>(
      side, basis, qn_gamma, qin_b, qout_b, q_b, o_b, ffn_gamma, fin_b, fout_b,
      w_qin, w_qout, w_q, w_o, w_fin, w_fout, kbuf, vbuf,
      sscale, pscale, skipsc, (float*)d_out);
}

// Round 4
// 1079.739 us; speedup vs baseline: 1.0279x; 1.0198x over previous
//
#include <hip/hip_runtime.h>

// B=8, C=128, T=128, F=512, K=64 — bf16 MFMA pipeline (32x32x16 + 16x16x32)
static constexpr int Cc = 128, Tt = 128, Ff = 512, Kk = 64;
static constexpr int SR = 136;  // LDS activation row stride (bf16 elems), [64 f][136 c]
static constexpr int PR = 88;   // LDS P-matrix row stride

typedef __bf16 bf16x8 __attribute__((ext_vector_type(8)));
typedef __bf16 bf16x4 __attribute__((ext_vector_type(4)));
typedef float f32x16 __attribute__((ext_vector_type(16)));
typedef float f32x4 __attribute__((ext_vector_type(4)));

__device__ __forceinline__ f32x16 z16() {
  f32x16 v;
#pragma unroll
  for (int i = 0; i < 16; ++i) v[i] = 0.f;
  return v;
}
__device__ __forceinline__ f32x4 z4() {
  f32x4 v;
#pragma unroll
  for (int i = 0; i < 4; ++i) v[i] = 0.f;
  return v;
}
__device__ __forceinline__ float silu_f(float x) { return x / (1.0f + __expf(-x)); }

// ---------- RMSNorm variants (barrier-free; caller barriers around) ----------
// 256-thread: 4 threads/row, 32 c each.
__device__ __forceinline__ void rmsnorm256(const __bf16* __restrict__ src,
                                           __bf16* __restrict__ dst,
                                           const float* __restrict__ gamma, int tid) {
  const int f = tid >> 2, s2 = tid & 3;
  const __bf16* p = src + f * SR + s2 * 32;
  bf16x8 v[4];
  float sum = 0.f;
#pragma unroll
  for (int k = 0; k < 4; ++k) {
    v[k] = *(const bf16x8*)(p + k * 8);
#pragma unroll
    for (int j = 0; j < 8; ++j) { float x = (float)v[k][j]; sum += x * x; }
  }
  sum += __shfl_xor(sum, 1);
  sum += __shfl_xor(sum, 2);
  const float r = rsqrtf(sum * (1.f / 128.f) + 1e-6f);
  __bf16* q = dst + f * SR + s2 * 32;
#pragma unroll
  for (int k = 0; k < 4; ++k) {
    bf16x8 w;
#pragma unroll
    for (int j = 0; j < 8; ++j)
      w[j] = (__bf16)((float)v[k][j] * r * gamma[s2 * 32 + k * 8 + j]);
    *(bf16x8*)(q + k * 8) = w;
  }
}

// 512-thread: 8 threads/row, 16 c each (3-step shfl reduce, all intra-wave).
__device__ __forceinline__ void rmsnorm512(const __bf16* __restrict__ src,
                                           __bf16* __restrict__ dst,
                                           const float* __restrict__ gamma, int tid) {
  const int f = tid >> 3, s3 = tid & 7;
  const __bf16* p = src + f * SR + s3 * 16;
  bf16x8 v[2];
  float sum = 0.f;
#pragma unroll
  for (int k = 0; k < 2; ++k) {
    v[k] = *(const bf16x8*)(p + k * 8);
#pragma unroll
    for (int j = 0; j < 8; ++j) { float x = (float)v[k][j]; sum += x * x; }
  }
  sum += __shfl_xor(sum, 1);
  sum += __shfl_xor(sum, 2);
  sum += __shfl_xor(sum, 4);
  const float r = rsqrtf(sum * (1.f / 128.f) + 1e-6f);
  __bf16* q = dst + f * SR + s3 * 16;
#pragma unroll
  for (int k = 0; k < 2; ++k) {
    bf16x8 w;
#pragma unroll
    for (int j = 0; j < 8; ++j)
      w[j] = (__bf16)((float)v[k][j] * r * gamma[s3 * 16 + k * 8 + j]);
    *(bf16x8*)(q + k * 8) = w;
  }
}

// ---------- GEMM units ----------
// 4-wave (256 thr): wave = (o-pair <<1)|f-tile; two 32x32 tiles per wave.
template <typename EPI>
__device__ __forceinline__ void unit_std(const __bf16* __restrict__ X,
                                         const __bf16* __restrict__ W,
                                         int lane, int wave, EPI epi) {
  const int h = lane >> 5, ol = lane & 31;
  const int p = wave >> 1, mt = wave & 1;
  const int oA = p * 64 + ol;
  bf16x8 B0[8], B1[8];
#pragma unroll
  for (int s = 0; s < 8; ++s) {
    B0[s] = *(const bf16x8*)(W + (size_t)oA * 128 + s * 16 + h * 8);
    B1[s] = *(const bf16x8*)(W + (size_t)(oA + 32) * 128 + s * 16 + h * 8);
  }
  f32x16 a0 = z16(), a1 = z16();
  const __bf16* Ar = X + (mt * 32 + ol) * SR + h * 8;
#pragma unroll
  for (int s = 0; s < 8; ++s) {
    bf16x8 Af = *(const bf16x8*)(Ar + s * 16);
    a0 = __builtin_amdgcn_mfma_f32_32x32x16_bf16(Af, B0[s], a0, 0, 0, 0);
    a1 = __builtin_amdgcn_mfma_f32_32x32x16_bf16(Af, B1[s], a1, 0, 0, 0);
  }
  epi(a0, 0);
  epi(a1, 1);
}

// 8-wave (512 thr): wave = (o-group<<1)|f-half; ONE 32x32 tile per wave.
// o = (wave>>1)*32 + ol; f = (wave&1)*32 + (r&3)+8*(r>>2)+4*h.
// B-frags = 32 VGPR (stays register-resident), acc = 16 VGPR.
template <typename EPI>
__device__ __forceinline__ void unit8(const __bf16* __restrict__ X,
                                      const __bf16* __restrict__ W,
                                      int lane, int wave, EPI epi) {
  const int h = lane >> 5, ol = lane & 31;
  const int p = wave >> 1, mt = wave & 1;
  const int oA = p * 32 + ol;
  bf16x8 Bf[8];
#pragma unroll
  for (int s = 0; s < 8; ++s)
    Bf[s] = *(const bf16x8*)(W + (size_t)oA * 128 + s * 16 + h * 8);
  f32x16 a = z16();
  const __bf16* Ar = X + (mt * 32 + ol) * SR + h * 8;
#pragma unroll
  for (int s = 0; s < 8; ++s) {
    bf16x8 Af = *(const bf16x8*)(Ar + s * 16);
    a = __builtin_amdgcn_mfma_f32_32x32x16_bf16(Af, Bf[s], a, 0, 0, 0);
  }
  epi(a);
}

// ---------------- weight conversion ----------------
struct PrepArgs {
  const float* src[9];
  int n[9];
};
__global__ __launch_bounds__(256) void prep_kernel(PrepArgs pa, __bf16* __restrict__ dst) {
  int off = 0;
  for (int m = 0; m < 9; ++m) {
    const float* s = pa.src[m];
    int n = pa.n[m];
    for (int i = blockIdx.x * 256 + threadIdx.x; i < n; i += gridDim.x * 256)
      dst[off + i] = (__bf16)s[i];
    off += n;
  }
}

// ---------------- kv kernel (unchanged structure, 4-wave) ----------------
__global__ __launch_bounds__(256, 4)
void kv_kernel(const float* __restrict__ latent, const float* __restrict__ lp_gamma,
               const float* __restrict__ lp_b, const float* __restrict__ k_b,
               const float* __restrict__ v_b,
               const __bf16* __restrict__ w_lp, const __bf16* __restrict__ w_k,
               const __bf16* __restrict__ w_v,
               __bf16* __restrict__ kbuf, __bf16* __restrict__ vbuf) {
  __shared__ __align__(16) __bf16 S0[64 * SR];
  __shared__ __align__(16) __bf16 S1[64 * SR];
  const int tid = threadIdx.x;
  const int lane = tid & 63, wave = tid >> 6;
  const int h = lane >> 5, ol = lane & 31;
  const int fr = blockIdx.x;
  const int b = fr >> 7, t = fr & 127;
  const size_t lbase = ((size_t)b * Cc * Tt + t) * Kk;

#pragma unroll
  for (int i = 0; i < 32; ++i) {
    int idx = i * 256 + tid;
    int c = idx >> 6, kk = idx & 63;
    S0[kk * SR + c] = (__bf16)latent[lbase + (size_t)c * Tt * Kk + kk];
  }
  __syncthreads();
  rmsnorm256(S0, S0, lp_gamma, tid);
  __syncthreads();

  unit_std(S0, w_lp, lane, wave, [&](const f32x16& a, int tix) {
    int o = (wave >> 1) * 64 + tix * 32 + ol;
    int mt = wave & 1;
    float bb = lp_b[o];
#pragma unroll
    for (int r = 0; r < 16; ++r) {
      int f = mt * 32 + (r & 3) + 8 * (r >> 2) + 4 * h;
      S1[f * SR + o] = (__bf16)silu_f(a[r] + bb);
    }
  });
  __syncthreads();

  __bf16* kb = kbuf + (size_t)fr * 8192;
  unit_std(S1, w_k, lane, wave, [&](const f32x16& a, int tix) {
    int o = (wave >> 1) * 64 + tix * 32 + ol;
    int mt = wave & 1;
    float bb = k_b[o];
#pragma unroll
    for (int r = 0; r < 16; ++r) {
      int kkr = mt * 32 + (r & 3) + 8 * (r >> 2) + 4 * h;
      kb[kkr * 128 + o] = (__bf16)(a[r] + bb);
    }
  });
  __bf16* vb = vbuf + (size_t)fr * 8192;
  unit_std(S1, w_v, lane, wave, [&](const f32x16& a, int tix) {
    int o = (wave >> 1) * 64 + tix * 32 + ol;
    int mt = wave & 1;
    float bb = v_b[o];
    __bf16* vbo = vb + (size_t)o * 64 + mt * 32;
#pragma unroll
    for (int q = 0; q < 4; ++q) {
      bf16x4 pk;
      pk[0] = (__bf16)(a[4 * q + 0] + bb);
      pk[1] = (__bf16)(a[4 * q + 1] + bb);
      pk[2] = (__bf16)(a[4 * q + 2] + bb);
      pk[3] = (__bf16)(a[4 * q + 3] + bb);
      *(bf16x4*)(vbo + 8 * q + 4 * h) = pk;
    }
  });
}

// ---------------- main kernel: 512 threads, 8 waves ----------------
// Buffer liveness (PM aliases S1):
//   ph1: side->S0, rmsnorm in place
//   ph2: qmlp swiglu product -> S1
//   ph3: query_h -> S2
//   ph4: q -> S0
//   ph5: scores+softmax -> PM (waves 0-3; V-frags prefetched by all waves)
//   ph6: attended^T -> S0
//   ph7: hidden -> S1 (+skip from S2)
//   ph8: rmsnorm(S1) -> S2
//   ph9: ffn swiglu product -> S0
//   ph10: out = fout@S0 + S1 -> global
// LDS = 52224 B; VGPR cap 128 (512 thr, 4 waves/EU) -> 2 blocks/CU = 16 waves/CU.
__global__ __launch_bounds__(512, 4)
void main_kernel(const float* __restrict__ side, const float* __restrict__ basis,
                 const float* __restrict__ qn_gamma,
                 const float* __restrict__ qin_b, const float* __restrict__ qout_b,
                 const float* __restrict__ q_b, const float* __restrict__ o_b,
                 const float* __restrict__ ffn_gamma,
                 const float* __restrict__ fin_b, const float* __restrict__ fout_b,
                 const __bf16* __restrict__ w_qin, const __bf16* __restrict__ w_qout,
                 const __bf16* __restrict__ w_q, const __bf16* __restrict__ w_o,
                 const __bf16* __restrict__ w_fin, const __bf16* __restrict__ w_fout,
                 const __bf16* __restrict__ kbuf, const __bf16* __restrict__ vbuf,
                 const float* __restrict__ p_sscale, const float* __restrict__ p_pscale,
                 const float* __restrict__ p_skip, float* __restrict__ out) {
  __shared__ __align__(16) __bf16 S0[64 * SR];
  __shared__ __align__(16) __bf16 S1[64 * SR];
  __shared__ __align__(16) __bf16 S2[64 * SR];
  __bf16* const PM = S1;  // [64][PR] alias, 11264 B <= 17408 B
  const int tid = threadIdx.x;
  const int lane = tid & 63, wave = tid >> 6;  // wave in [0,8)
  const int h = lane >> 5, ol = lane & 31;
  const int bid = blockIdx.x;
  const int fr = bid >> 3, tile = bid & 7;
  const int b = fr >> 7, t = fr & 127;
  const int fbase = tile * 64;
  const size_t sbase = ((size_t)b * Cc * Tt + t) * Ff + fbase;
  const float sscale = *p_sscale, pscale = *p_pscale, skip = *p_skip;
  const __bf16* kfr = kbuf + (size_t)fr * 8192;
  const __bf16* vfr = vbuf + (size_t)fr * 8192;

  // phase 1: load side tile -> S0 [f][c] bf16; rmsnorm in place
#pragma unroll
  for (int i = 0; i < 16; ++i) {
    int idx = i * 512 + tid;
    int c = idx >> 6, f = idx & 63;
    S0[f * SR + c] = (__bf16)side[sbase + (size_t)c * Tt * Ff + f];
  }
  __syncthreads();
  rmsnorm512(S0, S0, qn_gamma, tid);
  __syncthreads();

  // phase 2: qmlp swiglu: gate then up*silu(gate) -> S1
  {
    float sg[16];
    unit8(S0, w_qin + 128 * 128, lane, wave, [&](const f32x16& a) {
      int o = (wave >> 1) * 32 + ol;
      float bb = qin_b[128 + o];
#pragma unroll
      for (int r = 0; r < 16; ++r) sg[r] = silu_f(a[r] + bb);
    });
    unit8(S0, w_qin, lane, wave, [&](const f32x16& a) {
      int o = (wave >> 1) * 32 + ol;
      int mt = wave & 1;
      float bb = qin_b[o];
#pragma unroll
      for (int r = 0; r < 16; ++r) {
        int f = mt * 32 + (r & 3) + 8 * (r >> 2) + 4 * h;
        S1[f * SR + o] = (__bf16)((a[r] + bb) * sg[r]);
      }
    });
  }
  __syncthreads();

  // phase 3: query_h -> S2
  unit8(S1, w_qout, lane, wave, [&](const f32x16& a) {
    int o = (wave >> 1) * 32 + ol;
    int mt = wave & 1;
    float bb = qout_b[o];
#pragma unroll
    for (int r = 0; r < 16; ++r) {
      int f = mt * 32 + (r & 3) + 8 * (r >> 2) + 4 * h;
      S2[f * SR + o] = (__bf16)(a[r] + bb);
    }
  });
  __syncthreads();

  // phase 4: q -> S0
  unit8(S2, w_q, lane, wave, [&](const f32x16& a) {
    int o = (wave >> 1) * 32 + ol;
    int mt = wave & 1;
    float bb = q_b[o];
#pragma unroll
    for (int r = 0; r < 16; ++r) {
      int f = mt * 32 + (r & 3) + 8 * (r >> 2) + 4 * h;
      S0[f * SR + o] = (__bf16)(a[r] + bb);
    }
  });
  __syncthreads();

  // prefetch ph6 V-fragments (independent of PM) to hide their latency under ph5
  bf16x8 Bv[4];
  {
    const __bf16* Vr = vfr + (size_t)((wave >> 1) * 32 + ol) * 64 + h * 8;
#pragma unroll
    for (int s = 0; s < 4; ++s) Bv[s] = *(const bf16x8*)(Vr + s * 16);
  }

  // phase 5: scores (16x16x32; waves 0-3 = f-groups of 16) + in-wave softmax -> PM
  if (wave < 4) {
    const int q4 = lane >> 4, li = lane & 15;
    const int fw = wave * 16;
    f32x4 acc[4] = {z4(), z4(), z4(), z4()};
    const __bf16* Ar = S0 + (fw + li) * SR + q4 * 8;
    const __bf16* Kr = kfr + li * 128 + q4 * 8;
#pragma unroll
    for (int s = 0; s < 4; ++s) {
      bf16x8 Af = *(const bf16x8*)(Ar + s * 32);
#pragma unroll
      for (int nt = 0; nt < 4; ++nt) {
        bf16x8 Bf = *(const bf16x8*)(Kr + nt * (16 * 128) + s * 32);
        acc[nt] = __builtin_amdgcn_mfma_f32_16x16x32_bf16(Af, Bf, acc[nt], 0, 0, 0);
      }
    }
    float sc[4][4];
#pragma unroll
    for (int nt = 0; nt < 4; ++nt)
#pragma unroll
      for (int r = 0; r < 4; ++r) {
        int kk = 16 * nt + li;
        int f = fw + 4 * q4 + r;
        sc[nt][r] = acc[nt][r] * sscale + pscale * basis[(size_t)kk * Ff + fbase + f];
      }
#pragma unroll
    for (int r = 0; r < 4; ++r) {
      float m = fmaxf(fmaxf(sc[0][r], sc[1][r]), fmaxf(sc[2][r], sc[3][r]));
      m = fmaxf(m, __shfl_xor(m, 1));
      m = fmaxf(m, __shfl_xor(m, 2));
      m = fmaxf(m, __shfl_xor(m, 4));
      m = fmaxf(m, __shfl_xor(m, 8));
      float e[4], ssum = 0.f;
#pragma unroll
      for (int nt = 0; nt < 4; ++nt) { e[nt] = __expf(sc[nt][r] - m); ssum += e[nt]; }
      ssum += __shfl_xor(ssum, 1);
      ssum += __shfl_xor(ssum, 2);
      ssum += __shfl_xor(ssum, 4);
      ssum += __shfl_xor(ssum, 8);
      float inv = 1.f / ssum;
      int f = fw + 4 * q4 + r;
#pragma unroll
      for (int nt = 0; nt < 4; ++nt) PM[f * PR + 16 * nt + li] = (__bf16)(e[nt] * inv);
    }
  }
  __syncthreads();

  // phase 6: attended^T[f][c]; wave = (c-group<<1)|f-half; one 32x32 tile each -> S0
  {
    f32x16 a = z16();
    const __bf16* Ar = PM + ((wave & 1) * 32 + ol) * PR + h * 8;
#pragma unroll
    for (int s = 0; s < 4; ++s) {
      bf16x8 Af = *(const bf16x8*)(Ar + s * 16);
      a = __builtin_amdgcn_mfma_f32_32x32x16_bf16(Af, Bv[s], a, 0, 0, 0);
    }
    int c = (wave >> 1) * 32 + ol;
#pragma unroll
    for (int r = 0; r < 16; ++r) {
      int fl = (wave & 1) * 32 + (r & 3) + 8 * (r >> 2) + 4 * h;
      S0[fl * SR + c] = (__bf16)a[r];
    }
  }
  __syncthreads();

  // phase 7: hidden = o@attended + b + skip*qh -> S1 (PM dead)
  unit8(S0, w_o, lane, wave, [&](const f32x16& a) {
    int o = (wave >> 1) * 32 + ol;
    int mt = wave & 1;
    float bb = o_b[o];
#pragma unroll
    for (int r = 0; r < 16; ++r) {
      int f = mt * 32 + (r & 3) + 8 * (r >> 2) + 4 * h;
      S1[f * SR + o] = (__bf16)(a[r] + bb + skip * (float)S2[f * SR + o]);
    }
  });
  __syncthreads();

  // phase 8: ffn rmsnorm(hidden) -> S2
  rmsnorm512(S1, S2, ffn_gamma, tid);
  __syncthreads();

  // phase 9: ffn swiglu -> S0
  {
    float sg[16];
    unit8(S2, w_fin + 128 * 128, lane, wave, [&](const f32x16& a) {
      int o = (wave >> 1) * 32 + ol;
      float bb = fin_b[128 + o];
#pragma unroll
      for (int r = 0; r < 16; ++r) sg[r] = silu_f(a[r] + bb);
    });
    unit8(S2, w_fin, lane, wave, [&](const f32x16& a) {
      int o = (wave >> 1) * 32 + ol;
      int mt = wave & 1;
      float bb = fin_b[o];
#pragma unroll
      for (int r = 0; r < 16; ++r) {
        int f = mt * 32 + (r & 3) + 8 * (r >> 2) + 4 * h;
        S0[f * SR + o] = (__bf16)((a[r] + bb) * sg[r]);
      }
    });
  }
  __syncthreads();

  // phase 10: out = fout@prod + b + hidden(S1) -> global
  unit8(S0, w_fout, lane, wave, [&](const f32x16& a) {
    int o = (wave >> 1) * 32 + ol;
    int mt = wave & 1;
    float bb = fout_b[o];
    float* op = out + (((size_t)b * 128 + o) * 128 + t) * 512 + fbase + mt * 32;
#pragma unroll
    for (int q = 0; q < 4; ++q) {
      int f0l = 8 * q + 4 * h;
      float4 v;
      v.x = a[4 * q + 0] + bb + (float)S1[(mt * 32 + f0l + 0) * SR + o];
      v.y = a[4 * q + 1] + bb + (float)S1[(mt * 32 + f0l + 1) * SR + o];
      v.z = a[4 * q + 2] + bb + (float)S1[(mt * 32 + f0l + 2) * SR + o];
      v.w = a[4 * q + 3] + bb + (float)S1[(mt * 32 + f0l + 3) * SR + o];
      *(float4*)(op + f0l) = v;
    }
  });
}

extern "C" void kernel_launch(void* const* d_in, const int* in_sizes, int n_in,
                              void* d_out, int out_size, void* d_ws, size_t ws_size,
                              hipStream_t stream) {
  const float* latent    = (const float*)d_in[0];
  const float* side      = (const float*)d_in[1];
  const float* basis     = (const float*)d_in[2];
  const float* lp_gamma  = (const float*)d_in[3];
  const float* lp_w      = (const float*)d_in[4];
  const float* lp_b      = (const float*)d_in[5];
  const float* qn_gamma  = (const float*)d_in[6];
  const float* qin_w     = (const float*)d_in[7];
  const float* qin_b     = (const float*)d_in[8];
  const float* qout_w    = (const float*)d_in[9];
  const float* qout_b    = (const float*)d_in[10];
  const float* q_w       = (const float*)d_in[11];
  const float* q_b       = (const float*)d_in[12];
  const float* k_w       = (const float*)d_in[13];
  const float* k_b       = (const float*)d_in[14];
  const float* v_w       = (const float*)d_in[15];
  const float* v_b       = (const float*)d_in[16];
  const float* o_w       = (const float*)d_in[17];
  const float* o_b       = (const float*)d_in[18];
  const float* ffn_gamma = (const float*)d_in[19];
  const float* fin_w     = (const float*)d_in[20];
  const float* fin_b     = (const float*)d_in[21];
  const float* fout_w    = (const float*)d_in[22];
  const float* fout_b    = (const float*)d_in[23];
  const float* sscale    = (const float*)d_in[24];
  const float* pscale    = (const float*)d_in[25];
  const float* skipsc    = (const float*)d_in[26];

  __bf16* wsb = (__bf16*)d_ws;
  __bf16* kbuf = wsb;                                  // 1024*64*128
  __bf16* vbuf = wsb + (size_t)1024 * 8192;            // 1024*128*64
  __bf16* wbase = wsb + (size_t)2048 * 8192;
  // order: lp, qin, qout, q, k, v, o, fin, fout
  __bf16* w_lp   = wbase;
  __bf16* w_qin  = w_lp + 16384;
  __bf16* w_qout = w_qin + 32768;
  __bf16* w_q    = w_qout + 16384;
  __bf16* w_k    = w_q + 16384;
  __bf16* w_v    = w_k + 16384;
  __bf16* w_o    = w_v + 16384;
  __bf16* w_fin  = w_o + 16384;
  __bf16* w_fout = w_fin + 32768;

  PrepArgs pa;
  pa.src[0] = lp_w;   pa.n[0] = 16384;
  pa.src[1] = qin_w;  pa.n[1] = 32768;
  pa.src[2] = qout_w; pa.n[2] = 16384;
  pa.src[3] = q_w;    pa.n[3] = 16384;
  pa.src[4] = k_w;    pa.n[4] = 16384;
  pa.src[5] = v_w;    pa.n[5] = 16384;
  pa.src[6] = o_w;    pa.n[6] = 16384;
  pa.src[7] = fin_w;  pa.n[7] = 32768;
  pa.src[8] = fout_w; pa.n[8] = 16384;

  prep_kernel<<<dim3(64), dim3(256), 0, stream>>>(pa, wbase);
  kv_kernel<<<dim3(1024), dim3(256), 0, stream>>>(
      latent, lp_gamma, lp_b, k_b, v_b, w_lp, w_k, w_v, kbuf, vbuf);
  main_kernel<<<dim3(8192), dim3(512), 0, stream>>>(
      side, basis, qn_gamma, qin_b, qout_b, q_b, o_b, ffn_gamma, fin_b, fout_b,
      w_qin, w_qout, w_q, w_o, w_fin, w_fout, kbuf, vbuf,
      sscale, pscale, skipsc, (float*)d_out);
}